// Round 10
// baseline (2981.955 us; speedup 1.0000x reference)
//
#include <hip/hip_runtime.h>
#include <hip/hip_bf16.h>
#include <stdint.h>

#define IGNORE_INDEX (-100)

constexpr int kB2 = 8, kT = 1024, kH = 2048, kV = 32000;
constexpr int kM = kB2 * kT;           // 8192 token rows
constexpr int BM = 128, BN = 128, BK = 128;   // fp8: 128-B rows
constexpr int NSPLIT = 250;            // vocab splits (1 N-tile each)
constexpr int MBLKS = kM / BM;         // 64 row blocks
constexpr int KT = kH / BK;            // 16 K-tiles
constexpr int NWG = NSPLIT * MBLKS;    // 16000 workgroups

typedef int   i32x4  __attribute__((ext_vector_type(4)));
typedef int   i32x8  __attribute__((ext_vector_type(8)));
typedef float f32x4  __attribute__((ext_vector_type(4)));

// ---------------- cast fp32 -> fp8 e4m3 (OCP), optional pre-scale ----------------
__global__ void cast_to_fp8(const float* __restrict__ src, uint2* __restrict__ dst,
                            int n8, float scale) {
  int idx = blockIdx.x * blockDim.x + threadIdx.x;
  int stride = gridDim.x * blockDim.x;
  const float4* s = (const float4*)src;
  for (int i = idx; i < n8; i += stride) {
    float4 v0 = s[2 * i], v1 = s[2 * i + 1];
    int lo = 0, hi = 0;
    lo = __builtin_amdgcn_cvt_pk_fp8_f32(v0.x * scale, v0.y * scale, lo, false);
    lo = __builtin_amdgcn_cvt_pk_fp8_f32(v0.z * scale, v0.w * scale, lo, true);
    hi = __builtin_amdgcn_cvt_pk_fp8_f32(v1.x * scale, v1.y * scale, hi, false);
    hi = __builtin_amdgcn_cvt_pk_fp8_f32(v1.z * scale, v1.w * scale, hi, true);
    dst[i] = uint2{(unsigned)lo, (unsigned)hi};
  }
}

__device__ __forceinline__ void gload_lds16(const void* g, void* l) {
  __builtin_amdgcn_global_load_lds(
      (const __attribute__((address_space(1))) void*)g,
      (__attribute__((address_space(3))) void*)l, 16, 0, 0);
}

// ---------------- fused fp8 GEMM + logsumexp + target grab ----------------
// 128x128x128 tile, 4 waves (2M x 2N; wave = 64 rows x 64 cols), 2 LDS dbuf of
// 32KB -> 64KB total -> 2 BLOCKS/CU (the round-9 kernel's 128KB pinned us at 1
// block/CU; its 8-barrier lockstep stalls had nothing to overlap with — this
// round trades a little LDS-read efficiency for real cross-block concurrency).
// MFMA: mfma_scale_f32_16x16x128_f8f6f4, unit e8m0 scales (0x7F).
// Per tile (T3 minimal): stage(t+1 -> buf^1); read 16 ds_read_b128; 16 MFMA;
// vmcnt(0); ONE barrier. Loads get the whole tile's compute as flight time;
// the co-resident block fills the drain.
// LDS layout per buffer: A[128][128B] | B[128][128B]; chunk (row,j) holds
// global chunk (row, j^(row&7)) — pre-swizzled source, swizzled read (#21).
// C-layout 16x16 (dtype-independent, m89): col = lane&15, row = (lane>>4)*4+reg.
// Block->(split,mblk): XCD x owns A-panels mblk = x*8..x*8+7 (8 x 256KB = 2MB,
// L2-resident); sweeps all 250 splits per panel consecutively.
__global__ __launch_bounds__(256, 2) void fused_lse(
    const uint8_t* __restrict__ Wb,  // [V][H] fp8 (pre-scaled by 64)
    const uint8_t* __restrict__ Ab,  // [M][H] fp8
    const float* __restrict__ bias,  // [V]
    const int* __restrict__ target,  // [M]
    float4* __restrict__ partials)   // [NSPLIT][M] : (m, s, tgt_logit, 0)
{
  const int bid = blockIdx.x;
  const int x = bid & 7, j = bid >> 3;          // XCD, local index (2000 each)
  const int mblk  = x * 8 + j / NSPLIT;
  const int split = j % NSPLIT;

  const int tid = threadIdx.x;
  const int lane = tid & 63;
  const int w  = tid >> 6;     // 0..3
  const int wm = w >> 1;       // 0..1 : 64-row band
  const int wn = w & 1;        // 0..1 : 64-col half
  const int g  = lane >> 4;    // k-group (reads) / row-group (C layout)
  const int li = lane & 15;
  const int rowbase = mblk * BM;
  const int n0 = split * BN;

  __shared__ __align__(16) uint8_t lds[2][32768];   // per buf: A 16KB | B 16KB

  f32x4 acc[4][4];   // [m][n] : rows wm*64+m*16, cols wn*64+n*16
  const f32x4 vzero = {0.f, 0.f, 0.f, 0.f};
#pragma unroll
  for (int m = 0; m < 4; ++m)
#pragma unroll
    for (int n = 0; n < 4; ++n) acc[m][n] = vzero;

  // staging geometry (A and B tiles: 16 segs of 1KB each; wave w owns segs
  // 4w..4w+3). chunk c = seg*64+lane; row=c>>3, col=c&7; source col ^= row&7.
  int goff[4], lofs[4];
#pragma unroll
  for (int it = 0; it < 4; ++it) {
    int seg = 4 * w + it, c = seg * 64 + lane;
    int row = c >> 3, col = c & 7;
    goff[it] = row * kH + ((col ^ (row & 7)) << 4);   // fp8: row stride = kH bytes
    lofs[it] = seg * 1024;
  }

  const uint8_t* Agp = Ab + (size_t)rowbase * kH;
  const uint8_t* Bgp = Wb + (size_t)n0 * kH;

  // fragment rows
  int raM[4], rbN[4];
#pragma unroll
  for (int m = 0; m < 4; ++m) raM[m] = wm * 64 + m * 16 + li;
#pragma unroll
  for (int n = 0; n < 4; ++n) rbN[n] = wn * 64 + n * 16 + li;

  // read one 32B operand frag: lane's k-bytes [g*32, g*32+32) of row rr
  // (2 chunks 2g,2g+1, each XOR-swizzled) — 16-row span per ds_read_b128.
  auto RD = [&](const uint8_t* base, int rr) -> i32x8 {
    int c0 = g * 2;
    union { i32x4 q[2]; i32x8 o; } u;
    u.q[0] = *(const i32x4*)(base + rr * 128 + ((c0 ^ (rr & 7)) << 4));
    u.q[1] = *(const i32x4*)(base + rr * 128 + (((c0 + 1) ^ (rr & 7)) << 4));
    return u.o;
  };

#define MFMA8(am, bn, cc) \
  __builtin_amdgcn_mfma_scale_f32_16x16x128_f8f6f4((am), (bn), (cc), 0, 0, \
      0, 0x7F7F7F7F, 0, 0x7F7F7F7F)

  auto STAGE = [&](int t, int buf) {
    const int kb = t << 7;
    uint8_t* L = lds[buf];
#pragma unroll
    for (int it = 0; it < 4; ++it) gload_lds16(Agp + goff[it] + kb, L + lofs[it]);
#pragma unroll
    for (int it = 0; it < 4; ++it) gload_lds16(Bgp + goff[it] + kb, L + 16384 + lofs[it]);
  };

  // prologue: stage tile 0 into buf 0, drain
  STAGE(0, 0);
  asm volatile("s_waitcnt vmcnt(0)" ::: "memory");
  __builtin_amdgcn_s_barrier();

  for (int t = 0; t < KT; ++t) {
    if (t + 1 < KT) STAGE(t + 1, (t + 1) & 1);   // loads fly under this tile's work

    const uint8_t* As = lds[t & 1];
    const uint8_t* Bs = lds[t & 1] + 16384;
    i32x8 af[4], bn[4];
#pragma unroll
    for (int m = 0; m < 4; ++m) af[m] = RD(As, raM[m]);
#pragma unroll
    for (int n = 0; n < 4; ++n) bn[n] = RD(Bs, rbN[n]);
#pragma unroll
    for (int m = 0; m < 4; ++m)
#pragma unroll
      for (int n = 0; n < 4; ++n)
        acc[m][n] = MFMA8(af[m], bn[n], acc[m][n]);

    asm volatile("s_waitcnt vmcnt(0)" ::: "memory");  // next tile landed
    __builtin_amdgcn_s_barrier();                     // all waves done with buf
  }

  // ---- epilogue: undo W x64 pre-scale, bias, LSE partial + target grab ----
  const float inv64 = 0.015625f;
  float bv[4];
#pragma unroll
  for (int n = 0; n < 4; ++n) bv[n] = bias[n0 + wn * 64 + n * 16 + li];

  float4* mrg = (float4*)lds[0];   // [128 rows][2 wn] — all vmem drained
#pragma unroll
  for (int m = 0; m < 4; ++m)
#pragma unroll
    for (int i = 0; i < 4; ++i) {
      float xv[4];
#pragma unroll
      for (int n = 0; n < 4; ++n) xv[n] = acc[m][n][i] * inv64 + bv[n];
      float tmax = fmaxf(fmaxf(xv[0], xv[1]), fmaxf(xv[2], xv[3]));
#pragma unroll
      for (int d = 1; d <= 8; d <<= 1) tmax = fmaxf(tmax, __shfl_xor(tmax, d));
      float tsum = 0.f;
#pragma unroll
      for (int n = 0; n < 4; ++n) tsum += __expf(xv[n] - tmax);
#pragma unroll
      for (int d = 1; d <= 8; d <<= 1) tsum += __shfl_xor(tsum, d);
      int lrow = wm * 64 + m * 16 + g * 4 + i;
      int tv = target[rowbase + lrow];
      int c = ((tv == IGNORE_INDEX) ? 0 : tv) - (n0 + wn * 64);  // in [0,64)?
      float rt = 0.f;
#pragma unroll
      for (int n = 0; n < 4; ++n)
        rt += ((c >> 4) == n && (c & 15) == li) ? xv[n] : 0.f;
#pragma unroll
      for (int d = 1; d <= 8; d <<= 1) rt += __shfl_xor(rt, d);
      if (li == 0) mrg[lrow * 2 + wn] = float4{tmax, tsum, rt, 0.f};
    }
  __syncthreads();
  if (tid < BM) {
    float4 p0 = mrg[tid * 2 + 0], p1 = mrg[tid * 2 + 1];
    float mm = fmaxf(p0.x, p1.x);
    float ss = p0.y * __expf(p0.x - mm) + p1.y * __expf(p1.x - mm);
    partials[(size_t)split * kM + rowbase + tid] = float4{mm, ss, p0.z + p1.z, 0.f};
  }
#undef MFMA8
}

// ---------------- combine split partials -> per-token logp ----------------
// one wave per row; 64 lanes strided over splits, shfl LSE-merge. grid = kM/4.
__global__ __launch_bounds__(256) void combine_lse(
    const float4* __restrict__ partials, float* __restrict__ per_tok, int nsplit)
{
  int row  = blockIdx.x * 4 + (threadIdx.x >> 6);
  int lane = threadIdx.x & 63;
  float m = -1e30f, s = 0.f, t = 0.f;
  for (int sp = lane; sp < nsplit; sp += 64) {
    float4 p = partials[(size_t)sp * kM + row];
    t += p.z;
    float nm = fmaxf(m, p.x);
    s = s * __expf(m - nm) + p.y * __expf(p.x - nm);
    m = nm;
  }
#pragma unroll
  for (int d = 1; d < 64; d <<= 1) {
    float mo = __shfl_xor(m, d), so = __shfl_xor(s, d), to = __shfl_xor(t, d);
    float nm = fmaxf(m, mo);
    s = s * __expf(m - nm) + so * __expf(mo - nm);
    m = nm; t += to;
  }
  if (lane == 0) per_tok[row] = t - (m + logf(s));
}

// ---------------- final scalar loss ----------------
__global__ __launch_bounds__(1024) void final_loss(
    const float* __restrict__ per_tok, const int* __restrict__ target, float* __restrict__ out)
{
  __shared__ float redv[16], redc[16];
  __shared__ float ssum[8], scnt[8];
  int t = threadIdx.x;
  int wid = t >> 6, lane = t & 63;
  for (int b = 0; b < 8; ++b) {
    int row = b * 1024 + t;
    float mk = (target[row] != IGNORE_INDEX) ? 1.f : 0.f;
    float v = per_tok[row] * mk;
#pragma unroll
    for (int d = 1; d <= 32; d <<= 1) { v += __shfl_xor(v, d); mk += __shfl_xor(mk, d); }
    if (lane == 0) { redv[wid] = v; redc[wid] = mk; }
    __syncthreads();
    if (t == 0) {
      float sv = 0.f, sc = 0.f;
      for (int j = 0; j < 16; ++j) { sv += redv[j]; sc += redc[j]; }
      ssum[b] = sv; scnt[b] = sc;
    }
    __syncthreads();
  }
  if (t == 0) {
    float nsum = 0.f, ncnt = 0.f;
    for (int b = 0; b < 4; ++b) { nsum += ssum[b]; ncnt += scnt[b]; }
    float nll = -nsum / ncnt;
    float pref = 0.f;
    for (int b = 0; b < 4; ++b) {
      float avc = ssum[b] / scnt[b];
      float avr = ssum[b + 4] / scnt[b + 4];
      float d = 0.1f * (avc - avr);                 // BETA = 0.1
      float ls = (d >= 0.f) ? -log1pf(__expf(-d)) : d - log1pf(__expf(d));
      pref += ls;
    }
    pref *= 0.25f;                                  // mean over 4 pairs
    out[0] = 1.0f * nll - pref;                     // ALPHA = 1.0
  }
}

extern "C" void kernel_launch(void* const* d_in, const int* in_sizes, int n_in,
                              void* d_out, int out_size, void* d_ws, size_t ws_size,
                              hipStream_t stream) {
  const float* lin_weight = (const float*)d_in[0];  // [V][H]
  const float* input      = (const float*)d_in[1];  // [B2][T][H]
  const int*   target     = (const int*)d_in[2];    // [B2][T]
  const float* bias       = (const float*)d_in[3];  // [V]
  float* out = (float*)d_out;

  uint8_t* ws = (uint8_t*)d_ws;
  size_t offW = 0;
  size_t offA = offW + (size_t)kV * kH;                // 65,536,000 B (fp8)
  size_t offP = offA + (size_t)kM * kH;                // +16,777,216 B
  size_t offT = offP + (size_t)NSPLIT * kM * 16;       // +32,768,000 B
  size_t need = offT + (size_t)kM * 4;                 // ~115 MB (r4 proved >=181 MB)
  if (ws_size < need) return;  // clean failure signal (output stays 0)

  uint8_t* Wb = ws + offW;
  uint8_t* Ab = ws + offA;
  float4* partials = (float4*)(ws + offP);
  float*  per_tok  = (float*)(ws + offT);

  // W pre-scaled by 64 (escape e4m3 denormals; undone by inv64 in epilogue)
  cast_to_fp8<<<2048, 256, 0, stream>>>(lin_weight, (uint2*)Wb, kV * kH / 8, 64.0f);
  cast_to_fp8<<<1024, 256, 0, stream>>>(input, (uint2*)Ab, kM * kH / 8, 1.0f);
  fused_lse<<<NWG, 256, 0, stream>>>(Wb, Ab, bias, target, partials);
  combine_lse<<<kM / 4, 256, 0, stream>>>(partials, per_tok, NSPLIT);
  final_loss<<<1, 1024, 0, stream>>>(per_tok, target, out);
}

// Round 11
// 2972.442 us; speedup vs baseline: 1.0032x; 1.0032x over previous
//
#include <hip/hip_runtime.h>
#include <hip/hip_bf16.h>
#include <stdint.h>

#define IGNORE_INDEX (-100)

constexpr int kB2 = 8, kT = 1024, kH = 2048, kV = 32000;
constexpr int kM = kB2 * kT;           // 8192 token rows
constexpr int BM = 128, BN = 128, BK = 128;   // fp8: 128-B rows
constexpr int NSPLIT = 250;            // vocab splits (1 N-tile each)
constexpr int MBLKS = kM / BM;         // 64 row blocks
constexpr int KT = kH / BK;            // 16 K-tiles
constexpr int NWG = NSPLIT * MBLKS;    // 16000 workgroups

typedef int   i32x4  __attribute__((ext_vector_type(4)));
typedef int   i32x8  __attribute__((ext_vector_type(8)));
typedef float f32x4  __attribute__((ext_vector_type(4)));

// ---------------- cast fp32 -> fp8 e4m3 (OCP), optional pre-scale ----------------
__global__ void cast_to_fp8(const float* __restrict__ src, uint2* __restrict__ dst,
                            int n8, float scale) {
  int idx = blockIdx.x * blockDim.x + threadIdx.x;
  int stride = gridDim.x * blockDim.x;
  const float4* s = (const float4*)src;
  for (int i = idx; i < n8; i += stride) {
    float4 v0 = s[2 * i], v1 = s[2 * i + 1];
    int lo = 0, hi = 0;
    lo = __builtin_amdgcn_cvt_pk_fp8_f32(v0.x * scale, v0.y * scale, lo, false);
    lo = __builtin_amdgcn_cvt_pk_fp8_f32(v0.z * scale, v0.w * scale, lo, true);
    hi = __builtin_amdgcn_cvt_pk_fp8_f32(v1.x * scale, v1.y * scale, hi, false);
    hi = __builtin_amdgcn_cvt_pk_fp8_f32(v1.z * scale, v1.w * scale, hi, true);
    dst[i] = uint2{(unsigned)lo, (unsigned)hi};
  }
}

__device__ __forceinline__ void gload_lds16(const void* g, void* l) {
  __builtin_amdgcn_global_load_lds(
      (const __attribute__((address_space(1))) void*)g,
      (__attribute__((address_space(3))) void*)l, 16, 0, 0);
}

// ---------------- fused fp8 GEMM + logsumexp + target grab ----------------
// 128x128x128 tile, 4 waves (2M x 2N; wave = 64 rows x 64 cols), 2 LDS dbuf of
// 32KB -> 64KB total -> 2 blocks/CU. Per tile (T3 minimal): stage(t+1 ->
// buf^1); 16 ds_read_b128; 16 MFMA; vmcnt(0); ONE barrier. Cross-block
// concurrency fills the drain.
// MFMA: mfma_scale_f32_16x16x128_f8f6f4, unit e8m0 scales (0x7F).
// Block map (r10 POST-MORTEM FIX): r10's map had concurrent per-XCD blocks
// sweep 250 distinct W slices (16MB >> 4MB L2) -> 6.4GB fetch, 4.5TB/s fabric
// thrash, MfmaUtil 8%. Now k = bid>>3 decomposes into groups of 64 = 8 mblks
// x 8 splits: concurrent per-XCD window = 8 A-panels (2MB, resident) + 8 W
// slices (2MB) = 4MB = L2. All XCDs sweep the same split window in step ->
// W is one 65MB pass, L3-broadcast to the 8 XCDs.
// LDS layout per buffer: A[128][128B] | B[128][128B]; chunk (row,j) holds
// global chunk (row, j^(row&7)) — pre-swizzled source, swizzled read (#21).
// C-layout 16x16 (dtype-independent, m89): col = lane&15, row = (lane>>4)*4+reg.
__global__ __launch_bounds__(256, 2) void fused_lse(
    const uint8_t* __restrict__ Wb,  // [V][H] fp8 (pre-scaled by 64)
    const uint8_t* __restrict__ Ab,  // [M][H] fp8
    const float* __restrict__ bias,  // [V]
    const int* __restrict__ target,  // [M]
    float4* __restrict__ partials)   // [NSPLIT][M] : (m, s, tgt_logit, 0)
{
  const int bid = blockIdx.x;
  const int x = bid & 7;            // XCD (round-robin dispatch)
  const int k = bid >> 3;           // per-XCD sequence 0..1999
  int mloc, split;
  if (k < 1984) { int sg = k >> 6, r6 = k & 63; mloc = r6 >> 3; split = sg * 8 + (r6 & 7); }
  else          { int r6 = k - 1984;            mloc = r6 >> 1; split = 248 + (r6 & 1); }
  const int mblk = x * 8 + mloc;

  const int tid = threadIdx.x;
  const int lane = tid & 63;
  const int w  = tid >> 6;     // 0..3
  const int wm = w >> 1;       // 0..1 : 64-row band
  const int wn = w & 1;        // 0..1 : 64-col half
  const int g  = lane >> 4;    // k-group (reads) / row-group (C layout)
  const int li = lane & 15;
  const int rowbase = mblk * BM;
  const int n0 = split * BN;

  __shared__ __align__(16) uint8_t lds[2][32768];   // per buf: A 16KB | B 16KB

  f32x4 acc[4][4];   // [m][n] : rows wm*64+m*16, cols wn*64+n*16
  const f32x4 vzero = {0.f, 0.f, 0.f, 0.f};
#pragma unroll
  for (int m = 0; m < 4; ++m)
#pragma unroll
    for (int n = 0; n < 4; ++n) acc[m][n] = vzero;

  // staging geometry (A and B tiles: 16 segs of 1KB each; wave w owns segs
  // 4w..4w+3). chunk c = seg*64+lane; row=c>>3, col=c&7; source col ^= row&7.
  int goff[4], lofs[4];
#pragma unroll
  for (int it = 0; it < 4; ++it) {
    int seg = 4 * w + it, c = seg * 64 + lane;
    int row = c >> 3, col = c & 7;
    goff[it] = row * kH + ((col ^ (row & 7)) << 4);   // fp8: row stride = kH bytes
    lofs[it] = seg * 1024;
  }

  const uint8_t* Agp = Ab + (size_t)rowbase * kH;
  const uint8_t* Bgp = Wb + (size_t)n0 * kH;

  // fragment rows
  int raM[4], rbN[4];
#pragma unroll
  for (int m = 0; m < 4; ++m) raM[m] = wm * 64 + m * 16 + li;
#pragma unroll
  for (int n = 0; n < 4; ++n) rbN[n] = wn * 64 + n * 16 + li;

  // read one 32B operand frag: lane's k-bytes [g*32, g*32+32) of row rr
  // (2 chunks 2g,2g+1, each XOR-swizzled) — 16-row span per ds_read_b128.
  auto RD = [&](const uint8_t* base, int rr) -> i32x8 {
    int c0 = g * 2;
    union { i32x4 q[2]; i32x8 o; } u;
    u.q[0] = *(const i32x4*)(base + rr * 128 + ((c0 ^ (rr & 7)) << 4));
    u.q[1] = *(const i32x4*)(base + rr * 128 + (((c0 + 1) ^ (rr & 7)) << 4));
    return u.o;
  };

#define MFMA8(am, bn, cc) \
  __builtin_amdgcn_mfma_scale_f32_16x16x128_f8f6f4((am), (bn), (cc), 0, 0, \
      0, 0x7F7F7F7F, 0, 0x7F7F7F7F)

  auto STAGE = [&](int t, int buf) {
    const int kb = t << 7;
    uint8_t* L = lds[buf];
#pragma unroll
    for (int it = 0; it < 4; ++it) gload_lds16(Agp + goff[it] + kb, L + lofs[it]);
#pragma unroll
    for (int it = 0; it < 4; ++it) gload_lds16(Bgp + goff[it] + kb, L + 16384 + lofs[it]);
  };

  // prologue: stage tile 0 into buf 0, drain
  STAGE(0, 0);
  asm volatile("s_waitcnt vmcnt(0)" ::: "memory");
  __builtin_amdgcn_s_barrier();

  for (int t = 0; t < KT; ++t) {
    if (t + 1 < KT) STAGE(t + 1, (t + 1) & 1);   // loads fly under this tile's work

    const uint8_t* As = lds[t & 1];
    const uint8_t* Bs = lds[t & 1] + 16384;
    i32x8 af[4], bn[4];
#pragma unroll
    for (int m = 0; m < 4; ++m) af[m] = RD(As, raM[m]);
#pragma unroll
    for (int n = 0; n < 4; ++n) bn[n] = RD(Bs, rbN[n]);
#pragma unroll
    for (int m = 0; m < 4; ++m)
#pragma unroll
      for (int n = 0; n < 4; ++n)
        acc[m][n] = MFMA8(af[m], bn[n], acc[m][n]);

    asm volatile("s_waitcnt vmcnt(0)" ::: "memory");  // next tile landed
    __builtin_amdgcn_s_barrier();                     // all waves done with buf
  }

  // ---- epilogue: undo W x64 pre-scale, bias, LSE partial + target grab ----
  const float inv64 = 0.015625f;
  float bv[4];
#pragma unroll
  for (int n = 0; n < 4; ++n) bv[n] = bias[n0 + wn * 64 + n * 16 + li];

  float4* mrg = (float4*)lds[0];   // [128 rows][2 wn] — all vmem drained
#pragma unroll
  for (int m = 0; m < 4; ++m)
#pragma unroll
    for (int i = 0; i < 4; ++i) {
      float xv[4];
#pragma unroll
      for (int n = 0; n < 4; ++n) xv[n] = acc[m][n][i] * inv64 + bv[n];
      float tmax = fmaxf(fmaxf(xv[0], xv[1]), fmaxf(xv[2], xv[3]));
#pragma unroll
      for (int d = 1; d <= 8; d <<= 1) tmax = fmaxf(tmax, __shfl_xor(tmax, d));
      float tsum = 0.f;
#pragma unroll
      for (int n = 0; n < 4; ++n) tsum += __expf(xv[n] - tmax);
#pragma unroll
      for (int d = 1; d <= 8; d <<= 1) tsum += __shfl_xor(tsum, d);
      int lrow = wm * 64 + m * 16 + g * 4 + i;
      int tv = target[rowbase + lrow];
      int c = ((tv == IGNORE_INDEX) ? 0 : tv) - (n0 + wn * 64);  // in [0,64)?
      float rt = 0.f;
#pragma unroll
      for (int n = 0; n < 4; ++n)
        rt += ((c >> 4) == n && (c & 15) == li) ? xv[n] : 0.f;
#pragma unroll
      for (int d = 1; d <= 8; d <<= 1) rt += __shfl_xor(rt, d);
      if (li == 0) mrg[lrow * 2 + wn] = float4{tmax, tsum, rt, 0.f};
    }
  __syncthreads();
  if (tid < BM) {
    float4 p0 = mrg[tid * 2 + 0], p1 = mrg[tid * 2 + 1];
    float mm = fmaxf(p0.x, p1.x);
    float ss = p0.y * __expf(p0.x - mm) + p1.y * __expf(p1.x - mm);
    partials[(size_t)split * kM + rowbase + tid] = float4{mm, ss, p0.z + p1.z, 0.f};
  }
#undef MFMA8
}

// ---------------- combine split partials -> per-token logp ----------------
// one wave per row; 64 lanes strided over splits, shfl LSE-merge. grid = kM/4.
__global__ __launch_bounds__(256) void combine_lse(
    const float4* __restrict__ partials, float* __restrict__ per_tok, int nsplit)
{
  int row  = blockIdx.x * 4 + (threadIdx.x >> 6);
  int lane = threadIdx.x & 63;
  float m = -1e30f, s = 0.f, t = 0.f;
  for (int sp = lane; sp < nsplit; sp += 64) {
    float4 p = partials[(size_t)sp * kM + row];
    t += p.z;
    float nm = fmaxf(m, p.x);
    s = s * __expf(m - nm) + p.y * __expf(p.x - nm);
    m = nm;
  }
#pragma unroll
  for (int d = 1; d < 64; d <<= 1) {
    float mo = __shfl_xor(m, d), so = __shfl_xor(s, d), to = __shfl_xor(t, d);
    float nm = fmaxf(m, mo);
    s = s * __expf(m - nm) + so * __expf(mo - nm);
    m = nm; t += to;
  }
  if (lane == 0) per_tok[row] = t - (m + logf(s));
}

// ---------------- final scalar loss ----------------
__global__ __launch_bounds__(1024) void final_loss(
    const float* __restrict__ per_tok, const int* __restrict__ target, float* __restrict__ out)
{
  __shared__ float redv[16], redc[16];
  __shared__ float ssum[8], scnt[8];
  int t = threadIdx.x;
  int wid = t >> 6, lane = t & 63;
  for (int b = 0; b < 8; ++b) {
    int row = b * 1024 + t;
    float mk = (target[row] != IGNORE_INDEX) ? 1.f : 0.f;
    float v = per_tok[row] * mk;
#pragma unroll
    for (int d = 1; d <= 32; d <<= 1) { v += __shfl_xor(v, d); mk += __shfl_xor(mk, d); }
    if (lane == 0) { redv[wid] = v; redc[wid] = mk; }
    __syncthreads();
    if (t == 0) {
      float sv = 0.f, sc = 0.f;
      for (int j = 0; j < 16; ++j) { sv += redv[j]; sc += redc[j]; }
      ssum[b] = sv; scnt[b] = sc;
    }
    __syncthreads();
  }
  if (t == 0) {
    float nsum = 0.f, ncnt = 0.f;
    for (int b = 0; b < 4; ++b) { nsum += ssum[b]; ncnt += scnt[b]; }
    float nll = -nsum / ncnt;
    float pref = 0.f;
    for (int b = 0; b < 4; ++b) {
      float avc = ssum[b] / scnt[b];
      float avr = ssum[b + 4] / scnt[b + 4];
      float d = 0.1f * (avc - avr);                 // BETA = 0.1
      float ls = (d >= 0.f) ? -log1pf(__expf(-d)) : d - log1pf(__expf(d));
      pref += ls;
    }
    pref *= 0.25f;                                  // mean over 4 pairs
    out[0] = 1.0f * nll - pref;                     // ALPHA = 1.0
  }
}

extern "C" void kernel_launch(void* const* d_in, const int* in_sizes, int n_in,
                              void* d_out, int out_size, void* d_ws, size_t ws_size,
                              hipStream_t stream) {
  const float* lin_weight = (const float*)d_in[0];  // [V][H]
  const float* input      = (const float*)d_in[1];  // [B2][T][H]
  const int*   target     = (const int*)d_in[2];    // [B2][T]
  const float* bias       = (const float*)d_in[3];  // [V]
  float* out = (float*)d_out;

  uint8_t* ws = (uint8_t*)d_ws;
  size_t offW = 0;
  size_t offA = offW + (size_t)kV * kH;                // 65,536,000 B (fp8)
  size_t offP = offA + (size_t)kM * kH;                // +16,777,216 B
  size_t offT = offP + (size_t)NSPLIT * kM * 16;       // +32,768,000 B
  size_t need = offT + (size_t)kM * 4;                 // ~115 MB
  if (ws_size < need) return;  // clean failure signal (output stays 0)

  uint8_t* Wb = ws + offW;
  uint8_t* Ab = ws + offA;
  float4* partials = (float4*)(ws + offP);
  float*  per_tok  = (float*)(ws + offT);

  // W pre-scaled by 64 (escape e4m3 denormals; undone by inv64 in epilogue)
  cast_to_fp8<<<2048, 256, 0, stream>>>(lin_weight, (uint2*)Wb, kV * kH / 8, 64.0f);
  cast_to_fp8<<<1024, 256, 0, stream>>>(input, (uint2*)Ab, kM * kH / 8, 1.0f);
  fused_lse<<<NWG, 256, 0, stream>>>(Wb, Ab, bias, target, partials);
  combine_lse<<<kM / 4, 256, 0, stream>>>(partials, per_tok, NSPLIT);
  final_loss<<<1, 1024, 0, stream>>>(per_tok, target, out);
}

// Round 12
// 683.003 us; speedup vs baseline: 4.3659x; 4.3520x over previous
//
#include <hip/hip_runtime.h>
#include <hip/hip_bf16.h>
#include <stdint.h>

#define IGNORE_INDEX (-100)

constexpr int kB2 = 8, kT = 1024, kH = 2048, kV = 32000;
constexpr int kM = kB2 * kT;           // 8192 token rows
constexpr int BM = 256, BN = 256, BK = 128;   // fp8: 128-B rows
constexpr int NSPLIT = 125;            // vocab splits (1 N-tile each)
constexpr int MBLKS = kM / BM;         // 32 row blocks
constexpr int KT = kH / BK;            // 16 K-tiles
constexpr int NWG = NSPLIT * MBLKS;    // 4000 workgroups

typedef int   i32x4  __attribute__((ext_vector_type(4)));
typedef int   i32x8  __attribute__((ext_vector_type(8)));
typedef float f32x4  __attribute__((ext_vector_type(4)));

// ---------------- cast fp32 -> fp8 e4m3 (OCP), optional pre-scale ----------------
__global__ void cast_to_fp8(const float* __restrict__ src, uint2* __restrict__ dst,
                            int n8, float scale) {
  int idx = blockIdx.x * blockDim.x + threadIdx.x;
  int stride = gridDim.x * blockDim.x;
  const float4* s = (const float4*)src;
  for (int i = idx; i < n8; i += stride) {
    float4 v0 = s[2 * i], v1 = s[2 * i + 1];
    int lo = 0, hi = 0;
    lo = __builtin_amdgcn_cvt_pk_fp8_f32(v0.x * scale, v0.y * scale, lo, false);
    lo = __builtin_amdgcn_cvt_pk_fp8_f32(v0.z * scale, v0.w * scale, lo, true);
    hi = __builtin_amdgcn_cvt_pk_fp8_f32(v1.x * scale, v1.y * scale, hi, false);
    hi = __builtin_amdgcn_cvt_pk_fp8_f32(v1.z * scale, v1.w * scale, hi, true);
    dst[i] = uint2{(unsigned)lo, (unsigned)hi};
  }
}

__device__ __forceinline__ void gload_lds16(const void* g, void* l) {
  __builtin_amdgcn_global_load_lds(
      (const __attribute__((address_space(1))) void*)g,
      (__attribute__((address_space(3))) void*)l, 16, 0, 0);
}

// ---------------- fused fp8 GEMM + logsumexp + target grab ----------------
// REVERT to the round-9 kernel (660us, FETCH 388MB, proven) with ONE change:
// the K-tile is processed in 2 phases instead of 4 (4 barriers/tile, 16-MFMA
// bursts) — r9's 8 barriers with 8-MFMA bursts were the measured overhead
// (6350 cyc/tile vs 2212 MFMA floor). r10/r11's 128^2/2-block restructure was
// a map-insensitive catastrophe (6.3GB symmetric L2-thrash traffic) — do not
// shrink tiles with this staging scheme.
// 256x256x128 tile, 8 waves (4M x 2N; wave = 64 rows x 128 cols), 2 LDS dbuf.
// MFMA: mfma_scale_f32_16x16x128_f8f6f4 (fp8 x fp8, unit e8m0 scales 0x7F).
// Per K-tile: ph0 {read af[4] + B n=0..3; stage A(t+1); bar; 16 MFMA; bar}
//             ph1 {read B n=4..7;        stage B(t+1); bar; 16 MFMA; drain; bar}
// LDS layout per buffer: A[256][128B] | B[256][128B]; chunk (row,j) holds
// global chunk (row, j^(row&7)) — pre-swizzled source, swizzled read (#21).
// C-layout 16x16 (dtype-independent, m89): col = lane&15, row = (lane>>4)*4+reg.
// Block->(split,mblk) map: r9's XCD-affinity grouping (FETCH 388MB proven).
__global__ __launch_bounds__(512, 2) void fused_lse(
    const uint8_t* __restrict__ Wb,  // [V][H] fp8 (pre-scaled by 64)
    const uint8_t* __restrict__ Ab,  // [M][H] fp8
    const float* __restrict__ bias,  // [V]
    const int* __restrict__ target,  // [M]
    float4* __restrict__ partials)   // [NSPLIT][M] : (m, s, tgt_logit, 0)
{
  const int bid = blockIdx.x;
  const int gg = bid >> 8, r = bid & 255;
  int split, mblk;
  if (gg < 15) { int j = r >> 3; split = gg * 8 + (j & 7); mblk = (r & 7) * 4 + (j >> 3); }
  else         { split = 120 + (r >> 5); mblk = r & 31; }   // last group: 5 splits x 32

  const int tid = threadIdx.x;
  const int lane = tid & 63;
  const int w  = tid >> 6;     // 0..7
  const int wm = w >> 1;       // 0..3 : 64-row band
  const int wn = w & 1;        // 0..1 : 128-col half
  const int g  = lane >> 4;    // k-group (reads) / row-group (C layout)
  const int li = lane & 15;
  const int rowbase = mblk * BM;
  const int n0 = split * BN;

  __shared__ __align__(16) uint8_t lds[2][65536];   // per buf: A 32KB | B 32KB

  f32x4 acc[4][8];   // [m][n] : rows wm*64+m*16, cols wn*128+n*16
  const f32x4 vzero = {0.f, 0.f, 0.f, 0.f};
#pragma unroll
  for (int m = 0; m < 4; ++m)
#pragma unroll
    for (int n = 0; n < 8; ++n) acc[m][n] = vzero;

  // staging geometry (A and B tiles: 32 segs of 1KB each; wave w owns segs
  // 4w..4w+3). chunk c = seg*64+lane; row=c>>3, col=c&7; source col ^= row&7.
  int goff[4], lofs[4];
#pragma unroll
  for (int it = 0; it < 4; ++it) {
    int seg = 4 * w + it, c = seg * 64 + lane;
    int row = c >> 3, col = c & 7;
    goff[it] = row * kH + ((col ^ (row & 7)) << 4);   // fp8: row stride = kH bytes
    lofs[it] = seg * 1024;
  }

  const uint8_t* Agp = Ab + (size_t)rowbase * kH;
  const uint8_t* Bgp = Wb + (size_t)n0 * kH;

  // fragment rows
  int raM[4], rbN[8];
#pragma unroll
  for (int m = 0; m < 4; ++m) raM[m] = wm * 64 + m * 16 + li;
#pragma unroll
  for (int n = 0; n < 8; ++n) rbN[n] = wn * 128 + n * 16 + li;

  // read one 32B operand frag: lane's k-bytes [g*32, g*32+32) of row rr
  // (2 chunks 2g,2g+1, each XOR-swizzled) — 16-row span per ds_read_b128.
  auto RD = [&](const uint8_t* base, int rr) -> i32x8 {
    int c0 = g * 2;
    union { i32x4 q[2]; i32x8 o; } u;
    u.q[0] = *(const i32x4*)(base + rr * 128 + ((c0 ^ (rr & 7)) << 4));
    u.q[1] = *(const i32x4*)(base + rr * 128 + (((c0 + 1) ^ (rr & 7)) << 4));
    return u.o;
  };

#define MFMA8(am, bn, cc) \
  __builtin_amdgcn_mfma_scale_f32_16x16x128_f8f6f4((am), (bn), (cc), 0, 0, \
      0, 0x7F7F7F7F, 0, 0x7F7F7F7F)

  // prologue: stage tile 0 into buf 0, drain
#pragma unroll
  for (int it = 0; it < 4; ++it) gload_lds16(Agp + goff[it], lds[0] + lofs[it]);
#pragma unroll
  for (int it = 0; it < 4; ++it) gload_lds16(Bgp + goff[it], lds[0] + 32768 + lofs[it]);
  asm volatile("s_waitcnt vmcnt(0)" ::: "memory");
  __builtin_amdgcn_s_barrier();

  for (int t = 0; t < KT; ++t) {
    const uint8_t* As = lds[t & 1];
    const uint8_t* Bs = lds[t & 1] + 32768;
    uint8_t* Ld = lds[(t + 1) & 1];
    const int kb = (t + 1) << 7;         // next tile's K byte offset (128 B)
    const bool pf = (t + 1 < KT);        // workgroup-uniform
    i32x8 af[4], bq[4];

    // ---- phase 0: A frags + B n=0..3; stage A(t+1); 16 MFMA ----
#pragma unroll
    for (int m = 0; m < 4; ++m) af[m] = RD(As, raM[m]);
#pragma unroll
    for (int n = 0; n < 4; ++n) bq[n] = RD(Bs, rbN[n]);
    if (pf) {
#pragma unroll
      for (int it = 0; it < 4; ++it) gload_lds16(Agp + goff[it] + kb, Ld + lofs[it]);
    }
    __builtin_amdgcn_s_barrier();
    __builtin_amdgcn_s_setprio(1);
#pragma unroll
    for (int m = 0; m < 4; ++m)
#pragma unroll
      for (int n = 0; n < 4; ++n)
        acc[m][n] = MFMA8(af[m], bq[n], acc[m][n]);
    __builtin_amdgcn_s_setprio(0);
    __builtin_amdgcn_s_barrier();

    // ---- phase 1: B n=4..7; stage B(t+1); 16 MFMA; drain ----
#pragma unroll
    for (int n = 0; n < 4; ++n) bq[n] = RD(Bs, rbN[4 + n]);
    if (pf) {
#pragma unroll
      for (int it = 0; it < 4; ++it) gload_lds16(Bgp + goff[it] + kb, Ld + 32768 + lofs[it]);
    }
    __builtin_amdgcn_s_barrier();
    __builtin_amdgcn_s_setprio(1);
#pragma unroll
    for (int m = 0; m < 4; ++m)
#pragma unroll
      for (int n = 0; n < 4; ++n)
        acc[m][4 + n] = MFMA8(af[m], bq[n], acc[m][4 + n]);
    __builtin_amdgcn_s_setprio(0);
    if (pf) asm volatile("s_waitcnt vmcnt(0)" ::: "memory");  // next tile landed
    __builtin_amdgcn_s_barrier();
  }

  // ---- epilogue: undo W x64 pre-scale, bias, LSE partial + target grab ----
  const float inv64 = 0.015625f;
  float bv[8];
#pragma unroll
  for (int n = 0; n < 8; ++n) bv[n] = bias[n0 + wn * 128 + n * 16 + li];

  float4* mrg = (float4*)lds[0];   // [256 rows][2 wn] — all vmem drained
#pragma unroll
  for (int m = 0; m < 4; ++m)
#pragma unroll
    for (int i = 0; i < 4; ++i) {
      float x[8];
#pragma unroll
      for (int n = 0; n < 8; ++n) x[n] = acc[m][n][i] * inv64 + bv[n];
      float tmax = x[0];
#pragma unroll
      for (int n = 1; n < 8; ++n) tmax = fmaxf(tmax, x[n]);
#pragma unroll
      for (int d = 1; d <= 8; d <<= 1) tmax = fmaxf(tmax, __shfl_xor(tmax, d));
      float tsum = 0.f;
#pragma unroll
      for (int n = 0; n < 8; ++n) tsum += __expf(x[n] - tmax);
#pragma unroll
      for (int d = 1; d <= 8; d <<= 1) tsum += __shfl_xor(tsum, d);
      int lrow = wm * 64 + m * 16 + g * 4 + i;
      int tv = target[rowbase + lrow];
      int c = ((tv == IGNORE_INDEX) ? 0 : tv) - (n0 + wn * 128);  // in [0,128)?
      float rt = 0.f;
#pragma unroll
      for (int n = 0; n < 8; ++n)
        rt += ((c >> 4) == n && (c & 15) == li) ? x[n] : 0.f;
#pragma unroll
      for (int d = 1; d <= 8; d <<= 1) rt += __shfl_xor(rt, d);
      if (li == 0) mrg[lrow * 2 + wn] = float4{tmax, tsum, rt, 0.f};
    }
  __syncthreads();
  if (tid < BM) {
    float4 p0 = mrg[tid * 2 + 0], p1 = mrg[tid * 2 + 1];
    float mm = fmaxf(p0.x, p1.x);
    float ss = p0.y * __expf(p0.x - mm) + p1.y * __expf(p1.x - mm);
    partials[(size_t)split * kM + rowbase + tid] = float4{mm, ss, p0.z + p1.z, 0.f};
  }
#undef MFMA8
}

// ---------------- combine split partials -> per-token logp ----------------
// one wave per row; 64 lanes strided over splits, shfl LSE-merge. grid = kM/4.
__global__ __launch_bounds__(256) void combine_lse(
    const float4* __restrict__ partials, float* __restrict__ per_tok, int nsplit)
{
  int row  = blockIdx.x * 4 + (threadIdx.x >> 6);
  int lane = threadIdx.x & 63;
  float m = -1e30f, s = 0.f, t = 0.f;
  for (int sp = lane; sp < nsplit; sp += 64) {
    float4 p = partials[(size_t)sp * kM + row];
    t += p.z;
    float nm = fmaxf(m, p.x);
    s = s * __expf(m - nm) + p.y * __expf(p.x - nm);
    m = nm;
  }
#pragma unroll
  for (int d = 1; d < 64; d <<= 1) {
    float mo = __shfl_xor(m, d), so = __shfl_xor(s, d), to = __shfl_xor(t, d);
    float nm = fmaxf(m, mo);
    s = s * __expf(m - nm) + so * __expf(mo - nm);
    m = nm; t += to;
  }
  if (lane == 0) per_tok[row] = t - (m + logf(s));
}

// ---------------- final scalar loss ----------------
__global__ __launch_bounds__(1024) void final_loss(
    const float* __restrict__ per_tok, const int* __restrict__ target, float* __restrict__ out)
{
  __shared__ float redv[16], redc[16];
  __shared__ float ssum[8], scnt[8];
  int t = threadIdx.x;
  int wid = t >> 6, lane = t & 63;
  for (int b = 0; b < 8; ++b) {
    int row = b * 1024 + t;
    float mk = (target[row] != IGNORE_INDEX) ? 1.f : 0.f;
    float v = per_tok[row] * mk;
#pragma unroll
    for (int d = 1; d <= 32; d <<= 1) { v += __shfl_xor(v, d); mk += __shfl_xor(mk, d); }
    if (lane == 0) { redv[wid] = v; redc[wid] = mk; }
    __syncthreads();
    if (t == 0) {
      float sv = 0.f, sc = 0.f;
      for (int j = 0; j < 16; ++j) { sv += redv[j]; sc += redc[j]; }
      ssum[b] = sv; scnt[b] = sc;
    }
    __syncthreads();
  }
  if (t == 0) {
    float nsum = 0.f, ncnt = 0.f;
    for (int b = 0; b < 4; ++b) { nsum += ssum[b]; ncnt += scnt[b]; }
    float nll = -nsum / ncnt;
    float pref = 0.f;
    for (int b = 0; b < 4; ++b) {
      float avc = ssum[b] / scnt[b];
      float avr = ssum[b + 4] / scnt[b + 4];
      float d = 0.1f * (avc - avr);                 // BETA = 0.1
      float ls = (d >= 0.f) ? -log1pf(__expf(-d)) : d - log1pf(__expf(d));
      pref += ls;
    }
    pref *= 0.25f;                                  // mean over 4 pairs
    out[0] = 1.0f * nll - pref;                     // ALPHA = 1.0
  }
}

extern "C" void kernel_launch(void* const* d_in, const int* in_sizes, int n_in,
                              void* d_out, int out_size, void* d_ws, size_t ws_size,
                              hipStream_t stream) {
  const float* lin_weight = (const float*)d_in[0];  // [V][H]
  const float* input      = (const float*)d_in[1];  // [B2][T][H]
  const int*   target     = (const int*)d_in[2];    // [B2][T]
  const float* bias       = (const float*)d_in[3];  // [V]
  float* out = (float*)d_out;

  uint8_t* ws = (uint8_t*)d_ws;
  size_t offW = 0;
  size_t offA = offW + (size_t)kV * kH;                // 65,536,000 B (fp8)
  size_t offP = offA + (size_t)kM * kH;                // +16,777,216 B
  size_t offT = offP + (size_t)NSPLIT * kM * 16;       // +16,384,000 B
  size_t need = offT + (size_t)kM * 4;
  if (ws_size < need) return;  // clean failure signal (output stays 0)

  uint8_t* Wb = ws + offW;
  uint8_t* Ab = ws + offA;
  float4* partials = (float4*)(ws + offP);
  float*  per_tok  = (float*)(ws + offT);

  // W pre-scaled by 64 (escape e4m3 denormals; undone by inv64 in epilogue)
  cast_to_fp8<<<2048, 256, 0, stream>>>(lin_weight, (uint2*)Wb, kV * kH / 8, 64.0f);
  cast_to_fp8<<<1024, 256, 0, stream>>>(input, (uint2*)Ab, kM * kH / 8, 1.0f);
  fused_lse<<<NWG, 512, 0, stream>>>(Wb, Ab, bias, target, partials);
  combine_lse<<<kM / 4, 256, 0, stream>>>(partials, per_tok, NSPLIT);
  final_loss<<<1, 1024, 0, stream>>>(per_tok, target, out);
}

// Round 13
// 631.002 us; speedup vs baseline: 4.7257x; 1.0824x over previous
//
#include <hip/hip_runtime.h>
#include <hip/hip_bf16.h>
#include <stdint.h>

#define IGNORE_INDEX (-100)

constexpr int kB2 = 8, kT = 1024, kH = 2048, kV = 32000;
constexpr int kM = kB2 * kT;           // 8192 token rows
constexpr int BM = 256, BN = 256, BK = 128;   // fp8: 128-B rows
constexpr int NSPLIT = 125;            // vocab splits (1 N-tile each)
constexpr int MBLKS = kM / BM;         // 32 row blocks
constexpr int KT = kH / BK;            // 16 K-tiles
constexpr int NWG = NSPLIT * MBLKS;    // 4000 workgroups

typedef int   i32x4  __attribute__((ext_vector_type(4)));
typedef int   i32x8  __attribute__((ext_vector_type(8)));
typedef float f32x4  __attribute__((ext_vector_type(4)));

// ---------------- cast fp32 -> fp8 e4m3 (OCP), optional pre-scale ----------------
__global__ void cast_to_fp8(const float* __restrict__ src, uint2* __restrict__ dst,
                            int n8, float scale) {
  int idx = blockIdx.x * blockDim.x + threadIdx.x;
  int stride = gridDim.x * blockDim.x;
  const float4* s = (const float4*)src;
  for (int i = idx; i < n8; i += stride) {
    float4 v0 = s[2 * i], v1 = s[2 * i + 1];
    int lo = 0, hi = 0;
    lo = __builtin_amdgcn_cvt_pk_fp8_f32(v0.x * scale, v0.y * scale, lo, false);
    lo = __builtin_amdgcn_cvt_pk_fp8_f32(v0.z * scale, v0.w * scale, lo, true);
    hi = __builtin_amdgcn_cvt_pk_fp8_f32(v1.x * scale, v1.y * scale, hi, false);
    hi = __builtin_amdgcn_cvt_pk_fp8_f32(v1.z * scale, v1.w * scale, hi, true);
    dst[i] = uint2{(unsigned)lo, (unsigned)hi};
  }
}

__device__ __forceinline__ void gload_lds16(const void* g, void* l) {
  __builtin_amdgcn_global_load_lds(
      (const __attribute__((address_space(1))) void*)g,
      (__attribute__((address_space(3))) void*)l, 16, 0, 0);
}

// ---------------- fused fp8 GEMM + logsumexp + target grab ----------------
// r12 kernel with the phase structure collapsed to ONE phase / ONE barrier per
// K-tile:  STAGE(t+1 -> buf^1); interleaved {ds_read, MFMA}; vmcnt(0); barrier.
// The r9/r12 mid-tile barriers were correctness-unnecessary (stage writes
// buf^1, reads target buf; the end-of-tile barrier closes the reuse hazard
// because each wave's reads are consumed by its MFMAs before it can reach the
// barrier). Removing them lets the compiler interleave ds_read with MFMA and
// lets the 2 waves/SIMD slip within the tile — LDS pipe (~2313 cyc/tile) and
// MFMA pipe (~2211 cyc/tile) overlap instead of serializing (r12: 6336
// cyc/tile measured, 34% MfmaUtil).
// 256x256x128 tile, 8 waves (4M x 2N; wave = 64 rows x 128 cols), 2 LDS dbuf.
// MFMA: mfma_scale_f32_16x16x128_f8f6f4 (fp8 x fp8, unit e8m0 scales 0x7F).
// B-frags read in ping-pong pairs (bqa/bqb) to bound operand liveness.
// LDS layout per buffer: A[256][128B] | B[256][128B]; chunk (row,j) holds
// global chunk (row, j^(row&7)) — pre-swizzled source, swizzled read (#21).
// C-layout 16x16 (dtype-independent, m89): col = lane&15, row = (lane>>4)*4+reg.
// Block->(split,mblk) map: r9's XCD-affinity grouping (FETCH 388MB proven).
__global__ __launch_bounds__(512, 2) void fused_lse(
    const uint8_t* __restrict__ Wb,  // [V][H] fp8 (pre-scaled by 64)
    const uint8_t* __restrict__ Ab,  // [M][H] fp8
    const float* __restrict__ bias,  // [V]
    const int* __restrict__ target,  // [M]
    float4* __restrict__ partials)   // [NSPLIT][M] : (m, s, tgt_logit, 0)
{
  const int bid = blockIdx.x;
  const int gg = bid >> 8, r = bid & 255;
  int split, mblk;
  if (gg < 15) { int j = r >> 3; split = gg * 8 + (j & 7); mblk = (r & 7) * 4 + (j >> 3); }
  else         { split = 120 + (r >> 5); mblk = r & 31; }   // last group: 5 splits x 32

  const int tid = threadIdx.x;
  const int lane = tid & 63;
  const int w  = tid >> 6;     // 0..7
  const int wm = w >> 1;       // 0..3 : 64-row band
  const int wn = w & 1;        // 0..1 : 128-col half
  const int g  = lane >> 4;    // k-group (reads) / row-group (C layout)
  const int li = lane & 15;
  const int rowbase = mblk * BM;
  const int n0 = split * BN;

  __shared__ __align__(16) uint8_t lds[2][65536];   // per buf: A 32KB | B 32KB

  f32x4 acc[4][8];   // [m][n] : rows wm*64+m*16, cols wn*128+n*16
  const f32x4 vzero = {0.f, 0.f, 0.f, 0.f};
#pragma unroll
  for (int m = 0; m < 4; ++m)
#pragma unroll
    for (int n = 0; n < 8; ++n) acc[m][n] = vzero;

  // staging geometry (A and B tiles: 32 segs of 1KB each; wave w owns segs
  // 4w..4w+3). chunk c = seg*64+lane; row=c>>3, col=c&7; source col ^= row&7.
  int goff[4], lofs[4];
#pragma unroll
  for (int it = 0; it < 4; ++it) {
    int seg = 4 * w + it, c = seg * 64 + lane;
    int row = c >> 3, col = c & 7;
    goff[it] = row * kH + ((col ^ (row & 7)) << 4);   // fp8: row stride = kH bytes
    lofs[it] = seg * 1024;
  }

  const uint8_t* Agp = Ab + (size_t)rowbase * kH;
  const uint8_t* Bgp = Wb + (size_t)n0 * kH;

  // fragment rows
  int raM[4], rbN[8];
#pragma unroll
  for (int m = 0; m < 4; ++m) raM[m] = wm * 64 + m * 16 + li;
#pragma unroll
  for (int n = 0; n < 8; ++n) rbN[n] = wn * 128 + n * 16 + li;

  // read one 32B operand frag: lane's k-bytes [g*32, g*32+32) of row rr
  // (2 chunks 2g,2g+1, each XOR-swizzled) — 16-row span per ds_read_b128.
  auto RD = [&](const uint8_t* base, int rr) -> i32x8 {
    int c0 = g * 2;
    union { i32x4 q[2]; i32x8 o; } u;
    u.q[0] = *(const i32x4*)(base + rr * 128 + ((c0 ^ (rr & 7)) << 4));
    u.q[1] = *(const i32x4*)(base + rr * 128 + (((c0 + 1) ^ (rr & 7)) << 4));
    return u.o;
  };

#define MFMA8(am, bn, cc) \
  __builtin_amdgcn_mfma_scale_f32_16x16x128_f8f6f4((am), (bn), (cc), 0, 0, \
      0, 0x7F7F7F7F, 0, 0x7F7F7F7F)

  // prologue: stage tile 0 into buf 0, drain
#pragma unroll
  for (int it = 0; it < 4; ++it) gload_lds16(Agp + goff[it], lds[0] + lofs[it]);
#pragma unroll
  for (int it = 0; it < 4; ++it) gload_lds16(Bgp + goff[it], lds[0] + 32768 + lofs[it]);
  asm volatile("s_waitcnt vmcnt(0)" ::: "memory");
  __builtin_amdgcn_s_barrier();

  for (int t = 0; t < KT; ++t) {
    const uint8_t* As = lds[t & 1];
    const uint8_t* Bs = lds[t & 1] + 32768;
    uint8_t* Ld = lds[(t + 1) & 1];
    const int kb = (t + 1) << 7;         // next tile's K byte offset (128 B)
    const bool pf = (t + 1 < KT);        // workgroup-uniform

    // issue next tile's staging first — DMA flows under this tile's compute
    if (pf) {
#pragma unroll
      for (int it = 0; it < 4; ++it) gload_lds16(Agp + goff[it] + kb, Ld + lofs[it]);
#pragma unroll
      for (int it = 0; it < 4; ++it) gload_lds16(Bgp + goff[it] + kb, Ld + 32768 + lofs[it]);
    }

    // interleaved reads + MFMA (no mid barriers; compiler schedules lgkmcnt)
    i32x8 af[4], bqa0, bqa1, bqb0, bqb1;
#pragma unroll
    for (int m = 0; m < 4; ++m) af[m] = RD(As, raM[m]);
    bqa0 = RD(Bs, rbN[0]); bqa1 = RD(Bs, rbN[1]);
    bqb0 = RD(Bs, rbN[2]); bqb1 = RD(Bs, rbN[3]);
#pragma unroll
    for (int m = 0; m < 4; ++m) {
      acc[m][0] = MFMA8(af[m], bqa0, acc[m][0]);
      acc[m][1] = MFMA8(af[m], bqa1, acc[m][1]);
    }
    bqa0 = RD(Bs, rbN[4]); bqa1 = RD(Bs, rbN[5]);
#pragma unroll
    for (int m = 0; m < 4; ++m) {
      acc[m][2] = MFMA8(af[m], bqb0, acc[m][2]);
      acc[m][3] = MFMA8(af[m], bqb1, acc[m][3]);
    }
    bqb0 = RD(Bs, rbN[6]); bqb1 = RD(Bs, rbN[7]);
#pragma unroll
    for (int m = 0; m < 4; ++m) {
      acc[m][4] = MFMA8(af[m], bqa0, acc[m][4]);
      acc[m][5] = MFMA8(af[m], bqa1, acc[m][5]);
    }
#pragma unroll
    for (int m = 0; m < 4; ++m) {
      acc[m][6] = MFMA8(af[m], bqb0, acc[m][6]);
      acc[m][7] = MFMA8(af[m], bqb1, acc[m][7]);
    }

    if (pf) asm volatile("s_waitcnt vmcnt(0)" ::: "memory");  // next tile landed
    __builtin_amdgcn_s_barrier();   // buf handoff: all waves done reading/staging
  }

  // ---- epilogue: undo W x64 pre-scale, bias, LSE partial + target grab ----
  const float inv64 = 0.015625f;
  float bv[8];
#pragma unroll
  for (int n = 0; n < 8; ++n) bv[n] = bias[n0 + wn * 128 + n * 16 + li];

  float4* mrg = (float4*)lds[0];   // [256 rows][2 wn] — all vmem drained
#pragma unroll
  for (int m = 0; m < 4; ++m)
#pragma unroll
    for (int i = 0; i < 4; ++i) {
      float x[8];
#pragma unroll
      for (int n = 0; n < 8; ++n) x[n] = acc[m][n][i] * inv64 + bv[n];
      float tmax = x[0];
#pragma unroll
      for (int n = 1; n < 8; ++n) tmax = fmaxf(tmax, x[n]);
#pragma unroll
      for (int d = 1; d <= 8; d <<= 1) tmax = fmaxf(tmax, __shfl_xor(tmax, d));
      float tsum = 0.f;
#pragma unroll
      for (int n = 0; n < 8; ++n) tsum += __expf(x[n] - tmax);
#pragma unroll
      for (int d = 1; d <= 8; d <<= 1) tsum += __shfl_xor(tsum, d);
      int lrow = wm * 64 + m * 16 + g * 4 + i;
      int tv = target[rowbase + lrow];
      int c = ((tv == IGNORE_INDEX) ? 0 : tv) - (n0 + wn * 128);  // in [0,128)?
      float rt = 0.f;
#pragma unroll
      for (int n = 0; n < 8; ++n)
        rt += ((c >> 4) == n && (c & 15) == li) ? x[n] : 0.f;
#pragma unroll
      for (int d = 1; d <= 8; d <<= 1) rt += __shfl_xor(rt, d);
      if (li == 0) mrg[lrow * 2 + wn] = float4{tmax, tsum, rt, 0.f};
    }
  __syncthreads();
  if (tid < BM) {
    float4 p0 = mrg[tid * 2 + 0], p1 = mrg[tid * 2 + 1];
    float mm = fmaxf(p0.x, p1.x);
    float ss = p0.y * __expf(p0.x - mm) + p1.y * __expf(p1.x - mm);
    partials[(size_t)split * kM + rowbase + tid] = float4{mm, ss, p0.z + p1.z, 0.f};
  }
#undef MFMA8
}

// ---------------- combine split partials -> per-token logp ----------------
// one wave per row; 64 lanes strided over splits, shfl LSE-merge. grid = kM/4.
__global__ __launch_bounds__(256) void combine_lse(
    const float4* __restrict__ partials, float* __restrict__ per_tok, int nsplit)
{
  int row  = blockIdx.x * 4 + (threadIdx.x >> 6);
  int lane = threadIdx.x & 63;
  float m = -1e30f, s = 0.f, t = 0.f;
  for (int sp = lane; sp < nsplit; sp += 64) {
    float4 p = partials[(size_t)sp * kM + row];
    t += p.z;
    float nm = fmaxf(m, p.x);
    s = s * __expf(m - nm) + p.y * __expf(p.x - nm);
    m = nm;
  }
#pragma unroll
  for (int d = 1; d < 64; d <<= 1) {
    float mo = __shfl_xor(m, d), so = __shfl_xor(s, d), to = __shfl_xor(t, d);
    float nm = fmaxf(m, mo);
    s = s * __expf(m - nm) + so * __expf(mo - nm);
    m = nm; t += to;
  }
  if (lane == 0) per_tok[row] = t - (m + logf(s));
}

// ---------------- final scalar loss ----------------
__global__ __launch_bounds__(1024) void final_loss(
    const float* __restrict__ per_tok, const int* __restrict__ target, float* __restrict__ out)
{
  __shared__ float redv[16], redc[16];
  __shared__ float ssum[8], scnt[8];
  int t = threadIdx.x;
  int wid = t >> 6, lane = t & 63;
  for (int b = 0; b < 8; ++b) {
    int row = b * 1024 + t;
    float mk = (target[row] != IGNORE_INDEX) ? 1.f : 0.f;
    float v = per_tok[row] * mk;
#pragma unroll
    for (int d = 1; d <= 32; d <<= 1) { v += __shfl_xor(v, d); mk += __shfl_xor(mk, d); }
    if (lane == 0) { redv[wid] = v; redc[wid] = mk; }
    __syncthreads();
    if (t == 0) {
      float sv = 0.f, sc = 0.f;
      for (int j = 0; j < 16; ++j) { sv += redv[j]; sc += redc[j]; }
      ssum[b] = sv; scnt[b] = sc;
    }
    __syncthreads();
  }
  if (t == 0) {
    float nsum = 0.f, ncnt = 0.f;
    for (int b = 0; b < 4; ++b) { nsum += ssum[b]; ncnt += scnt[b]; }
    float nll = -nsum / ncnt;
    float pref = 0.f;
    for (int b = 0; b < 4; ++b) {
      float avc = ssum[b] / scnt[b];
      float avr = ssum[b + 4] / scnt[b + 4];
      float d = 0.1f * (avc - avr);                 // BETA = 0.1
      float ls = (d >= 0.f) ? -log1pf(__expf(-d)) : d - log1pf(__expf(d));
      pref += ls;
    }
    pref *= 0.25f;                                  // mean over 4 pairs
    out[0] = 1.0f * nll - pref;                     // ALPHA = 1.0
  }
}

extern "C" void kernel_launch(void* const* d_in, const int* in_sizes, int n_in,
                              void* d_out, int out_size, void* d_ws, size_t ws_size,
                              hipStream_t stream) {
  const float* lin_weight = (const float*)d_in[0];  // [V][H]
  const float* input      = (const float*)d_in[1];  // [B2][T][H]
  const int*   target     = (const int*)d_in[2];    // [B2][T]
  const float* bias       = (const float*)d_in[3];  // [V]
  float* out = (float*)d_out;

  uint8_t* ws = (uint8_t*)d_ws;
  size_t offW = 0;
  size_t offA = offW + (size_t)kV * kH;                // 65,536,000 B (fp8)
  size_t offP = offA + (size_t)kM * kH;                // +16,777,216 B
  size_t offT = offP + (size_t)NSPLIT * kM * 16;       // +16,384,000 B
  size_t need = offT + (size_t)kM * 4;
  if (ws_size < need) return;  // clean failure signal (output stays 0)

  uint8_t* Wb = ws + offW;
  uint8_t* Ab = ws + offA;
  float4* partials = (float4*)(ws + offP);
  float*  per_tok  = (float*)(ws + offT);

  // W pre-scaled by 64 (escape e4m3 denormals; undone by inv64 in epilogue)
  cast_to_fp8<<<2048, 256, 0, stream>>>(lin_weight, (uint2*)Wb, kV * kH / 8, 64.0f);
  cast_to_fp8<<<1024, 256, 0, stream>>>(input, (uint2*)Ab, kM * kH / 8, 1.0f);
  fused_lse<<<NWG, 512, 0, stream>>>(Wb, Ab, bias, target, partials);
  combine_lse<<<kM / 4, 256, 0, stream>>>(partials, per_tok, NSPLIT);
  final_loss<<<1, 1024, 0, stream>>>(per_tok, target, out);
}